// Round 16
// baseline (1368.525 us; speedup 1.0000x reference)
//
#include <hip/hip_runtime.h>
#include <hip/hip_bf16.h>
#include <math.h>

#define D_MODEL 3072
#define N_HEADS 24
#define DH 128
#define L_TXT 256
#define L_IMG 1024
#define L_ALL 1280
#define N_QKV 9216
#define N_MLP 12288
#define MOD_N 18432

typedef __attribute__((ext_vector_type(4))) float f32x4;
typedef __attribute__((ext_vector_type(8))) short bf16x8;

static __device__ __forceinline__ unsigned short f2bf(float f) {
  __hip_bfloat16 h = __float2bfloat16(f);
  union { __hip_bfloat16 h; unsigned short u; } v; v.h = h;
  return v.u;
}
static __device__ __forceinline__ unsigned pack2(float a, float b) {
  return (unsigned)f2bf(a) | ((unsigned)f2bf(b) << 16);
}

// ---------------------------------------------------------------- small ops
__global__ void silu_kernel(const float* __restrict__ vec, float* __restrict__ s) {
  int i = blockIdx.x * 256 + threadIdx.x;
  if (i < D_MODEL) { float x = vec[i]; s[i] = x / (1.f + expf(-x)); }
}

__global__ __launch_bounds__(256) void mod_gemv_partial(
    const float* __restrict__ s, const float* __restrict__ w_img,
    const float* __restrict__ w_txt, float* __restrict__ part) {
  int col4 = blockIdx.x * 256 + threadIdx.x;
  int kb = blockIdx.y;
  const float4* w4 = (const float4*)(blockIdx.z == 0 ? w_img : w_txt);
  float4 acc = {0.f, 0.f, 0.f, 0.f};
  int k0 = kb * 192;
  #pragma unroll 4
  for (int j = 0; j < 192; ++j) {
    float sv = s[k0 + j];
    float4 wv = w4[(size_t)(k0 + j) * 4608 + col4];
    acc.x = fmaf(sv, wv.x, acc.x);
    acc.y = fmaf(sv, wv.y, acc.y);
    acc.z = fmaf(sv, wv.z, acc.z);
    acc.w = fmaf(sv, wv.w, acc.w);
  }
  ((float4*)part)[(size_t)(blockIdx.z * 16 + kb) * 4608 + col4] = acc;
}

__global__ void mod_reduce(const float* __restrict__ part,
                           const float* __restrict__ b_img,
                           const float* __restrict__ b_txt,
                           float* __restrict__ modv) {
  int i = blockIdx.x * 256 + threadIdx.x;
  int st = i / MOD_N, col = i - st * MOD_N;
  float a = (st == 0) ? b_img[col] : b_txt[col];
  #pragma unroll
  for (int p = 0; p < 16; ++p) a += part[(st * 16 + p) * MOD_N + col];
  modv[i] = a;
}

// LN over D=3072 then (1+scale)*ln + shift, write bf16
__global__ __launch_bounds__(256) void ln_mod_kernel(
    const float* __restrict__ x, unsigned short* __restrict__ xm,
    const float* __restrict__ modv, int sh_off, int sc_off) {
  int row = blockIdx.x, t = threadIdx.x;
  int lane = t & 63, wid = t >> 6;
  const float4* xr = (const float4*)(x + (size_t)row * D_MODEL);
  float4 a = xr[t], b = xr[t + 256], c = xr[t + 512];
  float s = a.x + a.y + a.z + a.w + b.x + b.y + b.z + b.w + c.x + c.y + c.z + c.w;
  float q = a.x * a.x + a.y * a.y + a.z * a.z + a.w * a.w
          + b.x * b.x + b.y * b.y + b.z * b.z + b.w * b.w
          + c.x * c.x + c.y * c.y + c.z * c.z + c.w * c.w;
  #pragma unroll
  for (int m = 1; m < 64; m <<= 1) { s += __shfl_xor(s, m); q += __shfl_xor(q, m); }
  __shared__ float red[8];
  if (lane == 0) { red[wid] = s; red[4 + wid] = q; }
  __syncthreads();
  s = red[0] + red[1] + red[2] + red[3];
  q = red[4] + red[5] + red[6] + red[7];
  float mean = s * (1.f / 3072.f);
  float var = q * (1.f / 3072.f) - mean * mean;
  float inv = 1.f / sqrtf(var + 1e-6f);
  const float4* shp = (const float4*)(modv + sh_off);
  const float4* scp = (const float4*)(modv + sc_off);
  uint2* outp = (uint2*)(xm + (size_t)row * D_MODEL);
  float4 vals[3] = {a, b, c};
  #pragma unroll
  for (int j = 0; j < 3; ++j) {
    float4 sh = shp[t + j * 256], sc = scp[t + j * 256];
    float4 v = vals[j];
    float y0 = (v.x - mean) * inv * (1.f + sc.x) + sh.x;
    float y1 = (v.y - mean) * inv * (1.f + sc.y) + sh.y;
    float y2 = (v.z - mean) * inv * (1.f + sc.z) + sh.z;
    float y3 = (v.w - mean) * inv * (1.f + sc.w) + sh.w;
    uint2 o; o.x = pack2(y0, y1); o.y = pack2(y2, y3);
    outp[t + j * 256] = o;
  }
}

// ---------------------------------------------------------------- weight convert
// f32 [K][Nsrc] slice (cols ncol0..ncol0+Ndst) -> bf16 k-octet layout
// [K/8][Ndst][8]. Reads: 8 coalesced rows (256B/wave-instr). Writes: uint4
// contiguous. blockIdx.z = stream. grid (Ndst/256, K/8, 2).
__global__ __launch_bounds__(256) void wconv_kernel(
    const float* __restrict__ src0, const float* __restrict__ src1,
    unsigned short* __restrict__ dst, int Nsrc, int Ndst, int ncol0,
    size_t strm) {
  const float* src = blockIdx.z ? src1 : src0;
  unsigned short* d = dst + blockIdx.z * strm;
  int n = blockIdx.x * 256 + threadIdx.x;
  int ko = blockIdx.y;
  const float* s = src + (size_t)(ko * 8) * Nsrc + ncol0 + n;
  float v[8];
  #pragma unroll
  for (int i = 0; i < 8; ++i) v[i] = s[(size_t)i * Nsrc];
  uint4 p;
  p.x = pack2(v[0], v[1]); p.y = pack2(v[2], v[3]);
  p.z = pack2(v[4], v[5]); p.w = pack2(v[6], v[7]);
  *(uint4*)&d[((size_t)ko * Ndst + n) * 8] = p;
}

// ---------------------------------------------------------------- GEMM v16
// Pure-bf16, both operands via global_load_lds (m97 structure). W comes
// pre-converted in k-octet layout [K/8][Nw][8] so W staging = 2 glds/wave
// into Wlds [koct][1032] (16B pad/koct-row, wave w stages koct w, uniform
// base, lane x 16B dest). A unchanged (4 bufs, 2-phase, pre-swizzled src).
// Per phase issue order: W(i+1) x2, A(i+2) x2 -> barrier cluster with
// counted vmcnt(2) drains A(i+1)+W(i+1), leaves A(i+2) flying.
// 256 thr / 4 waves, tile 128M x 128N, BK=32, 48.5KB LDS, 3 blocks/CU.
// EPI 0: +bias -> f32   EPI 1: +bias, gelu -> bf16
// EPI 2: res + gate*(acc+bias) -> f32
template <int EPI>
__global__ __launch_bounds__(256, 3) void gemm16_kernel(
    const unsigned short* __restrict__ A0, const unsigned short* __restrict__ Wh0,
    const float* __restrict__ b0, float* __restrict__ oF0,
    unsigned short* __restrict__ oB0, const float* __restrict__ res0,
    const float* __restrict__ gate0,
    const unsigned short* __restrict__ A1, const unsigned short* __restrict__ Wh1,
    const float* __restrict__ b1, float* __restrict__ oF1,
    unsigned short* __restrict__ oB1, const float* __restrict__ res1,
    const float* __restrict__ gate1,
    int mi, int mt, int Nw, int Nout, int K) {
  __shared__ __align__(16) unsigned short Alds[4][4096]; // 4 bufs x 128 rows x 64B
  __shared__ __align__(16) unsigned short Wlds[2][4128]; // 2 bufs x 4 kocts x 1032

  const int MT = mi + mt;
  const int q8 = gridDim.x >> 3;  // grid % 8 == 0
  int orig = (blockIdx.x & 7) * q8 + (blockIdx.x >> 3);
  const int ntile = orig / MT;
  const int mrem = orig - ntile * MT;

  const unsigned short* A; const unsigned short* Wh; const float* bias;
  float* outF; unsigned short* outB; const float* res; const float* gate;
  int brow;
  if (mrem < mi) {
    A = A0; Wh = Wh0; bias = b0; outF = oF0; outB = oB0; res = res0; gate = gate0;
    brow = mrem * 128;
  } else {
    A = A1; Wh = Wh1; bias = b1; outF = oF1; outB = oB1; res = res1; gate = gate1;
    brow = (mrem - mi) * 128;
  }
  const int bcol = ntile * 128;

  const int tid = threadIdx.x, lane = tid & 63, wid = tid >> 6;
  const int lm = lane & 15, lk = lane >> 4;
  const int wr = (wid >> 1) * 64, wc = (wid & 1) * 64;
  const int aslot = lk ^ ((lm >> 1) & 3);

  // A staging: wave handles groups j = wid*2, wid*2+1 (16 rows each)
  const int arw = lane >> 2;
  const int achk = (lane & 3) ^ ((lane >> 3) & 3);
  // W staging: wave w stages koct w; lane covers n = bcol+l and bcol+64+l
  const size_t Nws = (size_t)Nw;

  f32x4 acc[4][4] = {};
  const int nt = K >> 5;

  auto STAGE_A = [&](int buf, int t) {
    const int kc = t * 32 + achk * 8;
    #pragma unroll
    for (int u = 0; u < 2; ++u) {
      const int j = wid * 2 + u;
      const unsigned short* g = A + (size_t)(brow + j * 16 + arw) * K + kc;
      __builtin_amdgcn_global_load_lds(g, &Alds[buf][j * 512], 16, 0, 0);
    }
  };
  auto STAGE_W = [&](int buf, int t) {
    const size_t base = ((size_t)(t * 4 + wid) * Nws + bcol) * 8;
    const unsigned short* g0 = Wh + base + (size_t)lane * 8;
    const unsigned short* g1 = g0 + 512;
    __builtin_amdgcn_global_load_lds(g0, &Wlds[buf][wid * 1032], 16, 0, 0);
    __builtin_amdgcn_global_load_lds(g1, &Wlds[buf][wid * 1032 + 512], 16, 0, 0);
  };
  auto MFMA16 = [&](int wbuf, int abuf) {
    bf16x8 bfr[4], af[4];
    #pragma unroll
    for (int nf = 0; nf < 4; ++nf)
      bfr[nf] = *(const bf16x8*)&Wlds[wbuf][lk * 1032 + (wc + nf * 16 + lm) * 8];
    #pragma unroll
    for (int mf = 0; mf < 4; ++mf) {
      const int row = wr + mf * 16 + lm;
      af[mf] = *(const bf16x8*)&Alds[abuf][row * 32 + aslot * 8];
    }
    __builtin_amdgcn_s_setprio(1);
    #pragma unroll
    for (int mf = 0; mf < 4; ++mf)
      #pragma unroll
      for (int nf = 0; nf < 4; ++nf)
        acc[mf][nf] = __builtin_amdgcn_mfma_f32_16x16x32_bf16(af[mf], bfr[nf], acc[mf][nf], 0, 0, 0);
    __builtin_amdgcn_s_setprio(0);
  };

  // prologue: A(0), W(0), A(1) -> drain A(0),W(0), keep A(1) flying
  STAGE_A(0, 0);
  STAGE_W(0, 0);
  STAGE_A(1, 1);
  __builtin_amdgcn_sched_barrier(0);
  asm volatile("s_waitcnt vmcnt(2)");
  __builtin_amdgcn_s_barrier();
  __builtin_amdgcn_sched_barrier(0);

  for (int i = 0; i < nt; ++i) {
    if (i + 1 < nt) STAGE_W((i + 1) & 1, i + 1);
    if (i + 2 < nt) STAGE_A((i + 2) & 3, i + 2);
    MFMA16(i & 1, i & 3);
    __builtin_amdgcn_sched_barrier(0);
    asm volatile("s_waitcnt lgkmcnt(0)");
    if (i + 2 < nt) asm volatile("s_waitcnt vmcnt(2)");
    else            asm volatile("s_waitcnt vmcnt(0)");
    __builtin_amdgcn_s_barrier();
    __builtin_amdgcn_sched_barrier(0);
  }

  #pragma unroll
  for (int nf = 0; nf < 4; ++nf) {
    int c = bcol + wc + nf * 16 + lm;
    float bv = bias[c];
    float gv = 0.f;
    if (EPI == 2) gv = gate[c];
    #pragma unroll
    for (int mf = 0; mf < 4; ++mf) {
      int r0 = brow + wr + mf * 16 + lk * 4;
      #pragma unroll
      for (int rg = 0; rg < 4; ++rg) {
        float v = acc[mf][nf][rg] + bv;
        size_t idx = (size_t)(r0 + rg) * Nout + c;
        if (EPI == 0) {
          outF[idx] = v;
        } else if (EPI == 1) {
          float g = 0.5f * v * (1.f + tanhf(0.7978845608028654f * (v + 0.044715f * v * v * v)));
          outB[idx] = f2bf(g);
        } else {
          outF[idx] = res[idx] + gv * v;
        }
      }
    }
  }
}

// ---------------------------------------------------------------- rms+rope+pack
__global__ __launch_bounds__(256) void rms_rope_kernel(
    const float* __restrict__ qkv_img, const float* __restrict__ qkv_txt,
    const float* __restrict__ img_qn, const float* __restrict__ img_kn,
    const float* __restrict__ txt_qn, const float* __restrict__ txt_kn,
    const float* __restrict__ pe, unsigned short* __restrict__ qa,
    unsigned short* __restrict__ ka, unsigned short* __restrict__ va) {
  int l = blockIdx.x * 4 + (threadIdx.x >> 6);
  int h = blockIdx.y;
  int t = threadIdx.x & 63;
  const float* base; const float* qn; const float* kn;
  if (l < L_TXT) { base = qkv_txt + (size_t)l * N_QKV; qn = txt_qn; kn = txt_kn; }
  else { base = qkv_img + (size_t)(l - L_TXT) * N_QKV; qn = img_qn; kn = img_kn; }
  int d0 = 2 * t;
  float q0 = base[h * DH + d0], q1 = base[h * DH + d0 + 1];
  float k0 = base[D_MODEL + h * DH + d0], k1 = base[D_MODEL + h * DH + d0 + 1];
  float v0 = base[2 * D_MODEL + h * DH + d0], v1 = base[2 * D_MODEL + h * DH + d0 + 1];
  float sq = q0 * q0 + q1 * q1, sk = k0 * k0 + k1 * k1;
  #pragma unroll
  for (int m = 1; m < 64; m <<= 1) { sq += __shfl_xor(sq, m); sk += __shfl_xor(sk, m); }
  float rq = 1.f / sqrtf(sq * (1.f / 128.f) + 1e-6f);
  float rk = 1.f / sqrtf(sk * (1.f / 128.f) + 1e-6f);
  q0 *= rq * qn[d0]; q1 *= rq * qn[d0 + 1];
  k0 *= rk * kn[d0]; k1 *= rk * kn[d0 + 1];
  const float* p = pe + ((size_t)l * 64 + t) * 4;
  float p00 = p[0], p01 = p[1], p10 = p[2], p11 = p[3];
  const float sc = 0.08838834764831845f; // 1/sqrt(128), folded into q
  float Q0 = (p00 * q0 + p01 * q1) * sc;
  float Q1 = (p10 * q0 + p11 * q1) * sc;
  float K0 = p00 * k0 + p01 * k1;
  float K1 = p10 * k0 + p11 * k1;
  size_t o = ((size_t)h * L_ALL + l) * 64 + t;
  ((unsigned*)qa)[o] = pack2(Q0, Q1);
  ((unsigned*)ka)[o] = pack2(K0, K1);
  ((unsigned*)va)[o] = pack2(v0, v1);
}

// ---------------------------------------------------------------- attention
static __device__ __forceinline__ void stage_v8(unsigned short* vp, int n0, uint4 v) {
  vp[(n0 + 0) * 8] = (unsigned short)v.x; vp[(n0 + 1) * 8] = (unsigned short)(v.x >> 16);
  vp[(n0 + 2) * 8] = (unsigned short)v.y; vp[(n0 + 3) * 8] = (unsigned short)(v.y >> 16);
  vp[(n0 + 4) * 8] = (unsigned short)v.z; vp[(n0 + 5) * 8] = (unsigned short)(v.z >> 16);
  vp[(n0 + 6) * 8] = (unsigned short)v.w; vp[(n0 + 7) * 8] = (unsigned short)(v.w >> 16);
}

__global__ __launch_bounds__(256) void attn_kernel(
    const unsigned short* __restrict__ qa, const unsigned short* __restrict__ ka,
    const unsigned short* __restrict__ va, unsigned short* __restrict__ out) {
  __shared__ __align__(16) unsigned short Ks[64 * 136];
  __shared__ __align__(16) unsigned short Vs[16 * 128 * 8]; // [kv/8][d][kv&7]
  __shared__ __align__(16) unsigned short Ps[4][16 * 72];
  int h = blockIdx.y, qt = blockIdx.x;
  int tid = threadIdx.x, lane = tid & 63, wid = tid >> 6;
  int lm = lane & 15, lk = lane >> 4;
  const unsigned short* qh = qa + (size_t)h * L_ALL * DH;
  const unsigned short* kh = ka + (size_t)h * L_ALL * DH;
  const unsigned short* vh = va + (size_t)h * L_ALL * DH;

  int qrow = qt * 64 + wid * 16 + lm;
  bf16x8 qf[4];
  #pragma unroll
  for (int kk = 0; kk < 4; ++kk)
    qf[kk] = *(const bf16x8*)(qh + (size_t)qrow * DH + kk * 32 + lk * 8);

  float m_run[4] = {-INFINITY, -INFINITY, -INFINITY, -INFINITY};
  float s_run[4] = {0.f, 0.f, 0.f, 0.f};
  f32x4 o[8] = {};

  int sr = tid >> 2, sc = (tid & 3) * 32; // staging: row, col0 (elems)

  for (int kt = 0; kt < L_ALL / 64; ++kt) {
    const uint4* kg = (const uint4*)(kh + (size_t)(kt * 64 + sr) * DH + sc);
    uint4 kv0 = kg[0], kv1 = kg[1], kv2 = kg[2], kv3 = kg[3];
    const uint4* vg = (const uint4*)(vh + (size_t)(kt * 64 + sr) * DH + sc);
    uint4 vv0 = vg[0], vv1 = vg[1], vv2 = vg[2], vv3 = vg[3];
    __syncthreads();
    uint4* kd = (uint4*)(&Ks[sr * 136 + sc]);
    kd[0] = kv0; kd[1] = kv1; kd[2] = kv2; kd[3] = kv3;
    {
      unsigned short* vp = &Vs[(sr >> 3) * 1024 + (sr & 7)];
      stage_v8(vp, sc, vv0); stage_v8(vp, sc + 8, vv1);
      stage_v8(vp, sc + 16, vv2); stage_v8(vp, sc + 24, vv3);
    }
    __syncthreads();

    f32x4 S[4] = {};
    #pragma unroll
    for (int kk = 0; kk < 4; ++kk)
      #pragma unroll
      for (int nf = 0; nf < 4; ++nf) {
        bf16x8 bv = *(const bf16x8*)(&Ks[(nf * 16 + lm) * 136 + kk * 32 + lk * 8]);
        S[nf] = __builtin_amdgcn_mfma_f32_16x16x32_bf16(qf[kk], bv, S[nf], 0, 0, 0);
      }

    float corr[4];
    #pragma unroll
    for (int r = 0; r < 4; ++r) {
      float mx = fmaxf(fmaxf(S[0][r], S[1][r]), fmaxf(S[2][r], S[3][r]));
      mx = fmaxf(mx, __shfl_xor(mx, 1));
      mx = fmaxf(mx, __shfl_xor(mx, 2));
      mx = fmaxf(mx, __shfl_xor(mx, 4));
      mx = fmaxf(mx, __shfl_xor(mx, 8));
      float mn = fmaxf(m_run[r], mx);
      corr[r] = expf(m_run[r] - mn);
      m_run[r] = mn;
    }
    float rs[4] = {0.f, 0.f, 0.f, 0.f};
    float pv[4][4];
    #pragma unroll
    for (int nf = 0; nf < 4; ++nf)
      #pragma unroll
      for (int r = 0; r < 4; ++r) {
        pv[nf][r] = expf(S[nf][r] - m_run[r]);
        rs[r] += pv[nf][r];
      }
    #pragma unroll
    for (int nf = 0; nf < 4; ++nf)
      #pragma unroll
      for (int r = 0; r < 4; ++r)
        Ps[wid][(lk * 4 + r) * 72 + nf * 16 + lm] = f2bf(pv[nf][r]);
    #pragma unroll
    for (int r = 0; r < 4; ++r) {
      rs[r] += __shfl_xor(rs[r], 1);
      rs[r] += __shfl_xor(rs[r], 2);
      rs[r] += __shfl_xor(rs[r], 4);
      rs[r] += __shfl_xor(rs[r], 8);
      s_run[r] = s_run[r] * corr[r] + rs[r];
    }
    #pragma unroll
    for (int nf = 0; nf < 8; ++nf)
      #pragma unroll
      for (int r = 0; r < 4; ++r)
        o[nf][r] *= corr[r];

    #pragma unroll
    for (int kk2 = 0; kk2 < 2; ++kk2) {
      bf16x8 pa = *(const bf16x8*)(&Ps[wid][lm * 72 + kk2 * 32 + lk * 8]);
      #pragma unroll
      for (int nf = 0; nf < 8; ++nf) {
        bf16x8 vb = *(const bf16x8*)(&Vs[((kk2 * 4 + lk) * 128 + nf * 16 + lm) * 8]);
        o[nf] = __builtin_amdgcn_mfma_f32_16x16x32_bf16(pa, vb, o[nf], 0, 0, 0);
      }
    }
  }

  float inv[4];
  #pragma unroll
  for (int r = 0; r < 4; ++r) inv[r] = 1.f / s_run[r];
  #pragma unroll
  for (int nf = 0; nf < 8; ++nf)
    #pragma unroll
    for (int r = 0; r < 4; ++r) {
      int row = qt * 64 + wid * 16 + lk * 4 + r;
      int col = h * DH + nf * 16 + lm;
      out[(size_t)row * D_MODEL + col] = f2bf(o[nf][r] * inv[r]);
    }
}

// ---------------------------------------------------------------- launch
extern "C" void kernel_launch(void* const* d_in, const int* in_sizes, int n_in,
                              void* d_out, int out_size, void* d_ws, size_t ws_size,
                              hipStream_t stream) {
  const float* img = (const float*)d_in[0];
  const float* txt = (const float*)d_in[1];
  const float* vec = (const float*)d_in[2];
  const float* pe = (const float*)d_in[3];
  const float* img_mod_w = (const float*)d_in[4];
  const float* img_mod_b = (const float*)d_in[5];
  const float* img_qkv_w = (const float*)d_in[6];
  const float* img_qkv_b = (const float*)d_in[7];
  const float* img_qnorm = (const float*)d_in[8];
  const float* img_knorm = (const float*)d_in[9];
  const float* img_proj_w = (const float*)d_in[10];
  const float* img_proj_b = (const float*)d_in[11];
  const float* img_mlp_w1 = (const float*)d_in[12];
  const float* img_mlp_b1 = (const float*)d_in[13];
  const float* img_mlp_w2 = (const float*)d_in[14];
  const float* img_mlp_b2 = (const float*)d_in[15];
  const float* txt_mod_w = (const float*)d_in[16];
  const float* txt_mod_b = (const float*)d_in[17];
  const float* txt_qkv_w = (const float*)d_in[18];
  const float* txt_qkv_b = (const float*)d_in[19];
  const float* txt_qnorm = (const float*)d_in[20];
  const float* txt_knorm = (const float*)d_in[21];
  const float* txt_proj_w = (const float*)d_in[22];
  const float* txt_proj_b = (const float*)d_in[23];
  const float* txt_mlp_w1 = (const float*)d_in[24];
  const float* txt_mlp_b1 = (const float*)d_in[25];
  const float* txt_mlp_w2 = (const float*)d_in[26];
  const float* txt_mlp_b2 = (const float*)d_in[27];

  char* wsb = (char*)d_ws;
  // layout (bytes):
  // 0         silu/part/modv  (2.52 MB)
  // 2523136   xm region -> attn out -> xm2   (7.86 MB)
  // 10387456  qkv f32 region -> img2/txt2 (15.73 MB used of 47.2)
  // 26116096  h_img/h_txt bf16 (31.5 MB)
  // 57573376  qa/ka/va (23.6 MB, dead after attn)  /  W^ region (75.5 MB max)
  //           peak ws = 57573376 + 75.5MB ~= 133 MB
  float* silu_s = (float*)(wsb + 0);
  float* part = (float*)(wsb + 16384);
  float* modv = (float*)(wsb + 2375680);
  unsigned short* xm_img = (unsigned short*)(wsb + 2523136);
  unsigned short* xm_txt = xm_img + (size_t)L_IMG * D_MODEL;
  float* qkv_img = (float*)(wsb + 10387456);
  float* qkv_txt = qkv_img + (size_t)L_IMG * N_QKV;
  unsigned short* qa = (unsigned short*)(wsb + 57573376);
  unsigned short* ka = (unsigned short*)(wsb + 65437696);
  unsigned short* va = (unsigned short*)(wsb + 73302016);
  unsigned short* attn = xm_img;                       // xm dead
  unsigned short* xm2_img = xm_img;                    // attn dead after proj
  unsigned short* xm2_txt = xm2_img + (size_t)L_IMG * D_MODEL;
  float* img2 = (float*)(wsb + 10387456);              // qkv f32 dead
  float* txt2 = img2 + (size_t)L_IMG * D_MODEL;
  unsigned short* h_img = (unsigned short*)(wsb + 26116096);
  unsigned short* h_txt = h_img + (size_t)L_IMG * N_MLP;
  unsigned short* Wc = (unsigned short*)(wsb + 57573376); // W^ region
  float* out_img = (float*)d_out;
  float* out_txt = out_img + (size_t)L_IMG * D_MODEL;
  float* mod_img = modv;
  float* mod_txt = modv + MOD_N;

  silu_kernel<<<12, 256, 0, stream>>>(vec, silu_s);
  mod_gemv_partial<<<dim3(18, 16, 2), 256, 0, stream>>>(silu_s, img_mod_w, txt_mod_w, part);
  mod_reduce<<<144, 256, 0, stream>>>(part, img_mod_b, txt_mod_b, modv);
  ln_mod_kernel<<<L_IMG, 256, 0, stream>>>(img, xm_img, mod_img, 0, 3072);
  ln_mod_kernel<<<L_TXT, 256, 0, stream>>>(txt, xm_txt, mod_txt, 0, 3072);

  // ---- qkv in two N-halves of 4608 (strm = 3072*4608 shorts)
  {
    const size_t strm = (size_t)D_MODEL * 4608;
    for (int hlf = 0; hlf < 2; ++hlf) {
      int nc = hlf * 4608;
      wconv_kernel<<<dim3(18, 384, 2), 256, 0, stream>>>(
          img_qkv_w, txt_qkv_w, Wc, N_QKV, 4608, nc, strm);
      gemm16_kernel<0><<<360, 256, 0, stream>>>(
          xm_img, Wc, img_qkv_b + nc, qkv_img + nc, nullptr, nullptr, nullptr,
          xm_txt, Wc + strm, txt_qkv_b + nc, qkv_txt + nc, nullptr, nullptr, nullptr,
          8, 2, 4608, N_QKV, D_MODEL);
    }
  }

  rms_rope_kernel<<<dim3(L_ALL / 4, N_HEADS), 256, 0, stream>>>(qkv_img, qkv_txt, img_qnorm, img_knorm, txt_qnorm, txt_knorm, pe, qa, ka, va);
  attn_kernel<<<dim3(L_ALL / 64, N_HEADS), 256, 0, stream>>>(qa, ka, va, attn);

  // ---- proj (full N=3072), EPI2: img2 = img + gate*(attn@W + b)
  {
    const size_t strm = (size_t)D_MODEL * D_MODEL;
    wconv_kernel<<<dim3(12, 384, 2), 256, 0, stream>>>(
        img_proj_w, txt_proj_w, Wc, D_MODEL, D_MODEL, 0, strm);
    gemm16_kernel<2><<<240, 256, 0, stream>>>(
        attn + (size_t)L_TXT * D_MODEL, Wc, img_proj_b, img2, nullptr, img, mod_img + 6144,
        attn, Wc + strm, txt_proj_b, txt2, nullptr, txt, mod_txt + 6144,
        8, 2, D_MODEL, D_MODEL, D_MODEL);
  }

  ln_mod_kernel<<<L_IMG, 256, 0, stream>>>(img2, xm2_img, mod_img, 9216, 12288);
  ln_mod_kernel<<<L_TXT, 256, 0, stream>>>(txt2, xm2_txt, mod_txt, 9216, 12288);

  // ---- mlp1 in two N-halves of 6144 (strm = 3072*6144)
  {
    const size_t strm = (size_t)D_MODEL * 6144;
    for (int hlf = 0; hlf < 2; ++hlf) {
      int nc = hlf * 6144;
      wconv_kernel<<<dim3(24, 384, 2), 256, 0, stream>>>(
          img_mlp_w1, txt_mlp_w1, Wc, N_MLP, 6144, nc, strm);
      gemm16_kernel<1><<<480, 256, 0, stream>>>(
          xm2_img, Wc, img_mlp_b1 + nc, nullptr, h_img + nc, nullptr, nullptr,
          xm2_txt, Wc + strm, txt_mlp_b1 + nc, nullptr, h_txt + nc, nullptr, nullptr,
          8, 2, 6144, N_MLP, D_MODEL);
    }
  }

  // ---- mlp2 in two N-halves of 1536 (K=12288, strm = 12288*1536)
  {
    const size_t strm = (size_t)N_MLP * 1536;
    for (int hlf = 0; hlf < 2; ++hlf) {
      int nc = hlf * 1536;
      wconv_kernel<<<dim3(6, 1536, 2), 256, 0, stream>>>(
          img_mlp_w2, txt_mlp_w2, Wc, D_MODEL, 1536, nc, strm);
      gemm16_kernel<2><<<120, 256, 0, stream>>>(
          h_img, Wc, img_mlp_b2 + nc, out_img + nc, nullptr, img2 + nc, mod_img + 15360 + nc,
          h_txt, Wc + strm, txt_mlp_b2 + nc, out_txt + nc, nullptr, txt2 + nc, mod_txt + 15360 + nc,
          8, 2, 1536, D_MODEL, N_MLP);
    }
  }
}